// Round 5
// baseline (255.632 us; speedup 1.0000x reference)
//
#include <hip/hip_runtime.h>
#include <hip/hip_bf16.h>

// ---------------------------------------------------------------------------
// GraphSAGE 3-layer forward. bf16 MFMA GEMMs (f32 accum), bf16 activations.
// Layers 0/1: direct aggregation + fused dual-phase GEMM:
//   M = segmean(X);  out = X@Wr + M@Wl + b   (one kernel, 2 stage+MFMA phases)
// Layer 2 commuted (aggregate in 64-d): A64=H@Wl2; B64=segmean(A64);
//   out = log_softmax(H@Wr2 + B64 + b2)  [fused epilogue]
// R5: latency fix — BM=64 (grid 782, ~3 blk/CU), weights read direct from
// global (L2-hot) instead of LDS, X double-buffer with early phase-1 loads.
// ---------------------------------------------------------------------------

#define WS_EPS 1e-5f

typedef unsigned short ushort_t;
typedef unsigned int uint_t;
typedef ushort_t ushort8 __attribute__((ext_vector_type(8)));
typedef short short8 __attribute__((ext_vector_type(8)));
typedef float f32x4 __attribute__((ext_vector_type(4)));

__device__ __forceinline__ float bf2f(ushort_t u) {
    return __uint_as_float(((uint_t)u) << 16);
}
__device__ __forceinline__ ushort_t f2bf(float f) {
    uint_t u = __float_as_uint(f);
    u = (u + 0x7fffu + ((u >> 16) & 1u)) >> 16;  // RNE
    return (ushort_t)u;
}

// ---- CSR build -------------------------------------------------------------
__global__ __launch_bounds__(256) void k_deg(const int* __restrict__ ei,
                                             int* __restrict__ deg, int E) {
    int e = blockIdx.x * 256 + threadIdx.x;
    if (e < E) atomicAdd(&deg[ei[E + e]], 1);
}

constexpr int SCHUNK = 4096;

__global__ __launch_bounds__(256) void k_scan_part(const int* __restrict__ deg,
                                                   int* __restrict__ bsum, int n) {
    int t = threadIdx.x;
    int base = blockIdx.x * SCHUNK + t * 16;
    int s = 0;
#pragma unroll
    for (int j = 0; j < 16; ++j) {
        int i = base + j;
        if (i < n) s += deg[i];
    }
#pragma unroll
    for (int d = 1; d < 64; d <<= 1) s += __shfl_xor(s, d);
    __shared__ int wt[4];
    if ((t & 63) == 0) wt[t >> 6] = s;
    __syncthreads();
    if (t == 0) bsum[blockIdx.x] = wt[0] + wt[1] + wt[2] + wt[3];
}

__global__ __launch_bounds__(64) void k_scan_bsum(const int* __restrict__ bsum,
                                                  int* __restrict__ boff,
                                                  int* __restrict__ off_n, int nb) {
    int lane = threadIdx.x;
    int carry = 0;
    for (int base = 0; base < nb; base += 64) {
        int t = base + lane;
        int v = (t < nb) ? bsum[t] : 0;
        int x = v;
#pragma unroll
        for (int d = 1; d < 64; d <<= 1) {
            int y = __shfl_up(x, d);
            if (lane >= d) x += y;
        }
        if (t < nb) boff[t] = carry + x - v;
        carry += __shfl(x, 63);
    }
    if (lane == 0) *off_n = carry;
}

__global__ __launch_bounds__(256) void k_scan_apply(const int* __restrict__ deg,
                                                    const int* __restrict__ boff,
                                                    int* __restrict__ off, int n) {
    int t = threadIdx.x;
    int lane = t & 63, wid = t >> 6;
    int base = blockIdx.x * SCHUNK + t * 16;
    int v[16];
    int s = 0;
#pragma unroll
    for (int j = 0; j < 16; ++j) {
        int i = base + j;
        v[j] = (i < n) ? deg[i] : 0;
        s += v[j];
    }
    int x = s;
#pragma unroll
    for (int d = 1; d < 64; d <<= 1) {
        int y = __shfl_up(x, d);
        if (lane >= d) x += y;
    }
    __shared__ int wtot[4];
    if (lane == 63) wtot[wid] = x;
    __syncthreads();
    int woff = 0;
    for (int wj = 0; wj < wid; ++wj) woff += wtot[wj];
    int run = boff[blockIdx.x] + woff + x - s;
#pragma unroll
    for (int j = 0; j < 16; ++j) {
        int i = base + j;
        if (i < n) off[i] = run;
        run += v[j];
    }
}

__global__ __launch_bounds__(256) void k_scatter(const int* __restrict__ ei,
                                                 const int* __restrict__ off,
                                                 int* __restrict__ cur,
                                                 int* __restrict__ csr, int E) {
    int e = blockIdx.x * 256 + threadIdx.x;
    if (e < E) {
        int d = ei[E + e];
        int s = ei[e];
        int p = atomicAdd(&cur[d], 1);
        csr[off[d] + p] = s;
    }
}

// ---- prep: x -> bf16 AND weights -> bf16 transposed, one launch -------------
__global__ __launch_bounds__(256) void k_prep(const float* __restrict__ x,
                                              ushort_t* __restrict__ xb, int total2,
                                              int nb_cvt,
                                              const float* __restrict__ Wl0,
                                              const float* __restrict__ Wr0,
                                              const float* __restrict__ Wl1,
                                              const float* __restrict__ Wr1,
                                              const float* __restrict__ Wl2,
                                              const float* __restrict__ Wr2,
                                              ushort_t* __restrict__ wts) {
    int b = blockIdx.x;
    if (b < nb_cvt) {
        int i = b * 256 + threadIdx.x;
        if (i >= total2) return;
        float2 v = *(const float2*)&x[(size_t)i * 2];
        uint_t p = (uint_t)f2bf(v.x) | ((uint_t)f2bf(v.y) << 16);
        *(uint_t*)&xb[(size_t)i * 2] = p;
        return;
    }
    int id = (b - nb_cvt) * 256 + threadIdx.x;
    if (id >= 81920) return;
    const float* W;
    int rel, nout, base;
    if (id < 65536) {
        int m = id >> 14;
        rel = id & 16383;
        nout = 128;
        base = m << 14;
        W = (m == 0) ? Wl0 : (m == 1) ? Wr0 : (m == 2) ? Wl1 : Wr1;
    } else {
        int m = (id - 65536) >> 13;
        rel = (id - 65536) & 8191;
        nout = 64;
        base = 65536 + (m << 13);
        W = (m == 0) ? Wl2 : Wr2;
    }
    int c = rel >> 7;
    int k = rel & 127;
    wts[base + rel] = f2bf(W[(size_t)k * nout + c]);
}

// ---- fused dual-phase GEMM (NOUT=128): out = X1@W1 + X2@W2 + bias ----------
// BM=64, 4 waves (2 row x 2 col), wave tile 32x64. B-fragments straight from
// global (W is 32KB, L2-hot). X staged in LDS, two buffers, early ph1 loads.
// EPI: 2 -> relu, bf16 out (layer 0). 1 -> f32 out + BN stats (layer 1).
template <int EPI>
__global__ __launch_bounds__(256, 4) void k_fgemm(const ushort_t* __restrict__ X1,
                                                  const ushort_t* __restrict__ W1,
                                                  const ushort_t* __restrict__ X2,
                                                  const ushort_t* __restrict__ W2,
                                                  const float* __restrict__ bias,
                                                  void* __restrict__ outv,
                                                  float* __restrict__ stats, int n) {
    constexpr int NOUT = 128, K = 128, BM = 64, LDK = 136;
    constexpr int FM = 2, FN = 4;

    __shared__ ushort_t Xs[2][BM * LDK];
    __shared__ float sred[256];

    const int t = threadIdx.x;
    const int row0 = blockIdx.x * BM;
    const int lane = t & 63;
    const int wid = t >> 6;
    const int wr = wid >> 1, wc = wid & 1;
    const int r16 = lane & 15, kb = lane >> 4;
    const int tr = t >> 4, seg = t & 15;

    if (EPI == 1) sred[t] = 0.f;

    // stage phase-0 X
    ushort8 g[4];
#pragma unroll
    for (int u = 0; u < 4; ++u) {
        int gr = row0 + u * 16 + tr;
        g[u] = (gr < n) ? *(const ushort8*)&X1[(size_t)gr * K + seg * 8] : (ushort8)0;
    }
#pragma unroll
    for (int u = 0; u < 4; ++u)
        *(ushort8*)&Xs[0][(u * 16 + tr) * LDK + seg * 8] = g[u];
    __syncthreads();

    // issue phase-1 X loads (overlap with phase-0 compute)
#pragma unroll
    for (int u = 0; u < 4; ++u) {
        int gr = row0 + u * 16 + tr;
        g[u] = (gr < n) ? *(const ushort8*)&X2[(size_t)gr * K + seg * 8] : (ushort8)0;
    }

    f32x4 acc[FM][FN];
#pragma unroll
    for (int i = 0; i < FM; ++i)
#pragma unroll
        for (int j = 0; j < FN; ++j) acc[i][j] = (f32x4)0.f;

    // phase 0: A from Xs[0], B from W1 (global, L2-hot)
#pragma unroll
    for (int ks = 0; ks < 4; ++ks) {
        short8 a[FM], b[FN];
#pragma unroll
        for (int fm = 0; fm < FM; ++fm)
            a[fm] = *(const short8*)&Xs[0][(wr * 32 + fm * 16 + r16) * LDK + ks * 32 + kb * 8];
#pragma unroll
        for (int fn = 0; fn < FN; ++fn)
            b[fn] = *(const short8*)&W1[(size_t)(wc * 64 + fn * 16 + r16) * K + ks * 32 + kb * 8];
#pragma unroll
        for (int fm = 0; fm < FM; ++fm)
#pragma unroll
            for (int fn = 0; fn < FN; ++fn)
                acc[fm][fn] = __builtin_amdgcn_mfma_f32_16x16x32_bf16(a[fm], b[fn], acc[fm][fn], 0, 0, 0);
    }

    // land phase-1 X, then compute
#pragma unroll
    for (int u = 0; u < 4; ++u)
        *(ushort8*)&Xs[1][(u * 16 + tr) * LDK + seg * 8] = g[u];
    __syncthreads();

#pragma unroll
    for (int ks = 0; ks < 4; ++ks) {
        short8 a[FM], b[FN];
#pragma unroll
        for (int fm = 0; fm < FM; ++fm)
            a[fm] = *(const short8*)&Xs[1][(wr * 32 + fm * 16 + r16) * LDK + ks * 32 + kb * 8];
#pragma unroll
        for (int fn = 0; fn < FN; ++fn)
            b[fn] = *(const short8*)&W2[(size_t)(wc * 64 + fn * 16 + r16) * K + ks * 32 + kb * 8];
#pragma unroll
        for (int fm = 0; fm < FM; ++fm)
#pragma unroll
            for (int fn = 0; fn < FN; ++fn)
                acc[fm][fn] = __builtin_amdgcn_mfma_f32_16x16x32_bf16(a[fm], b[fn], acc[fm][fn], 0, 0, 0);
    }

    if constexpr (EPI == 2) {
#pragma unroll
        for (int fm = 0; fm < FM; ++fm) {
#pragma unroll
            for (int r = 0; r < 4; ++r) {
                int row = row0 + wr * 32 + fm * 16 + kb * 4 + r;
                if (row >= n) continue;
#pragma unroll
                for (int fn = 0; fn < FN; ++fn) {
                    int col = wc * 64 + fn * 16 + r16;
                    float v = acc[fm][fn][r] + bias[col];
                    ((ushort_t*)outv)[(size_t)row * NOUT + col] = f2bf(fmaxf(v, 0.f));
                }
            }
        }
    } else {
        float s[FN], q[FN];
#pragma unroll
        for (int fn = 0; fn < FN; ++fn) { s[fn] = 0.f; q[fn] = 0.f; }
#pragma unroll
        for (int fm = 0; fm < FM; ++fm) {
#pragma unroll
            for (int r = 0; r < 4; ++r) {
                int row = row0 + wr * 32 + fm * 16 + kb * 4 + r;
                if (row >= n) continue;
#pragma unroll
                for (int fn = 0; fn < FN; ++fn) {
                    int col = wc * 64 + fn * 16 + r16;
                    float v = acc[fm][fn][r] + bias[col];
                    ((float*)outv)[(size_t)row * NOUT + col] = v;
                    s[fn] += v;
                    q[fn] += v * v;
                }
            }
        }
#pragma unroll
        for (int fn = 0; fn < FN; ++fn) {
            s[fn] += __shfl_xor(s[fn], 16);
            s[fn] += __shfl_xor(s[fn], 32);
            q[fn] += __shfl_xor(q[fn], 16);
            q[fn] += __shfl_xor(q[fn], 32);
        }
        if (kb == 0) {
#pragma unroll
            for (int fn = 0; fn < FN; ++fn) {
                int col = wc * 64 + fn * 16 + r16;
                atomicAdd(&sred[col], s[fn]);
                atomicAdd(&sred[128 + col], q[fn]);
            }
        }
        __syncthreads();
        atomicAdd(&stats[t], sred[t]);
    }
}

// ---- single GEMM (NOUT=64): BM=64, 4 waves all in M, wave tile 16x64 -------
// EPI: 0 -> bf16 out, no AGG; 3 -> +AGG+bias, fused log_softmax, f32 out.
template <int EPI>
__global__ __launch_bounds__(256, 4) void k_mgemm64(const ushort_t* __restrict__ X,
                                                    const ushort_t* __restrict__ WT,
                                                    const ushort_t* __restrict__ AGG,
                                                    const float* __restrict__ bias,
                                                    void* __restrict__ outv, int n) {
    constexpr int NOUT = 64, K = 128, BM = 64, LDK = 136;
    constexpr int FN = 4;

    __shared__ ushort_t Xs[BM * LDK];

    const int t = threadIdx.x;
    const int row0 = blockIdx.x * BM;
    const int lane = t & 63;
    const int wid = t >> 6;
    const int r16 = lane & 15, kb = lane >> 4;
    const int tr = t >> 4, seg = t & 15;

#pragma unroll
    for (int u = 0; u < 4; ++u) {
        int gr = row0 + u * 16 + tr;
        ushort8 v = (gr < n) ? *(const ushort8*)&X[(size_t)gr * K + seg * 8] : (ushort8)0;
        *(ushort8*)&Xs[(u * 16 + tr) * LDK + seg * 8] = v;
    }
    __syncthreads();

    f32x4 acc[FN];
#pragma unroll
    for (int j = 0; j < FN; ++j) acc[j] = (f32x4)0.f;

#pragma unroll
    for (int ks = 0; ks < 4; ++ks) {
        short8 a = *(const short8*)&Xs[(wid * 16 + r16) * LDK + ks * 32 + kb * 8];
        short8 b[FN];
#pragma unroll
        for (int fn = 0; fn < FN; ++fn)
            b[fn] = *(const short8*)&WT[(size_t)(fn * 16 + r16) * K + ks * 32 + kb * 8];
#pragma unroll
        for (int fn = 0; fn < FN; ++fn)
            acc[fn] = __builtin_amdgcn_mfma_f32_16x16x32_bf16(a, b[fn], acc[fn], 0, 0, 0);
    }

    if constexpr (EPI == 3) {
        float* outp = (float*)outv;
#pragma unroll
        for (int r = 0; r < 4; ++r) {
            int row = row0 + wid * 16 + kb * 4 + r;
            bool ok = (row < n);
            float vv[FN];
#pragma unroll
            for (int fn = 0; fn < FN; ++fn) {
                int col = fn * 16 + r16;
                vv[fn] = ok ? (acc[fn][r] + bf2f(AGG[(size_t)row * NOUT + col]) + bias[col])
                            : 0.f;
            }
            float m = fmaxf(fmaxf(vv[0], vv[1]), fmaxf(vv[2], vv[3]));
#pragma unroll
            for (int d = 1; d < 16; d <<= 1) m = fmaxf(m, __shfl_xor(m, d));
            float e = expf(vv[0] - m) + expf(vv[1] - m) + expf(vv[2] - m) + expf(vv[3] - m);
#pragma unroll
            for (int d = 1; d < 16; d <<= 1) e += __shfl_xor(e, d);
            float lg = m + logf(e);
            if (ok) {
#pragma unroll
                for (int fn = 0; fn < FN; ++fn)
                    outp[(size_t)row * NOUT + fn * 16 + r16] = vv[fn] - lg;
            }
        }
    } else {
#pragma unroll
        for (int r = 0; r < 4; ++r) {
            int row = row0 + wid * 16 + kb * 4 + r;
            if (row >= n) continue;
#pragma unroll
            for (int fn = 0; fn < FN; ++fn) {
                int col = fn * 16 + r16;
                ((ushort_t*)outv)[(size_t)row * NOUT + col] = f2bf(acc[fn][r]);
            }
        }
    }
}

// ---- segment mean over CSR, bf16 in/out, f32 accum, 8-deep MLP --------------
template <int D>
__global__ __launch_bounds__(256) void k_segmean_bf(const ushort_t* __restrict__ U,
                                                    const int* __restrict__ off,
                                                    const int* __restrict__ srcs,
                                                    ushort_t* __restrict__ out,
                                                    int n) {
    int node = blockIdx.x * 8 + (threadIdx.x >> 5);
    int sub = threadIdx.x & 31;
    if (node >= n) return;
    int beg = off[node], end = off[node + 1];
    constexpr int CPL = D / 32;
    float a0 = 0.f, a1 = 0.f, a2 = 0.f, a3 = 0.f;
    int i = beg;
    for (; i + 8 <= end; i += 8) {
        int sv[8];
#pragma unroll
        for (int u = 0; u < 8; ++u) sv[u] = srcs[i + u];
#pragma unroll
        for (int u = 0; u < 8; ++u) {
            if (CPL == 4) {
                uint2 v = *(const uint2*)&U[(size_t)sv[u] * D + sub * 4];
                a0 += __uint_as_float(v.x << 16);
                a1 += __uint_as_float(v.x & 0xffff0000u);
                a2 += __uint_as_float(v.y << 16);
                a3 += __uint_as_float(v.y & 0xffff0000u);
            } else {
                uint_t v = *(const uint_t*)&U[(size_t)sv[u] * D + sub * 2];
                a0 += __uint_as_float(v << 16);
                a1 += __uint_as_float(v & 0xffff0000u);
            }
        }
    }
    for (; i + 4 <= end; i += 4) {
        int sv[4];
#pragma unroll
        for (int u = 0; u < 4; ++u) sv[u] = srcs[i + u];
#pragma unroll
        for (int u = 0; u < 4; ++u) {
            if (CPL == 4) {
                uint2 v = *(const uint2*)&U[(size_t)sv[u] * D + sub * 4];
                a0 += __uint_as_float(v.x << 16);
                a1 += __uint_as_float(v.x & 0xffff0000u);
                a2 += __uint_as_float(v.y << 16);
                a3 += __uint_as_float(v.y & 0xffff0000u);
            } else {
                uint_t v = *(const uint_t*)&U[(size_t)sv[u] * D + sub * 2];
                a0 += __uint_as_float(v << 16);
                a1 += __uint_as_float(v & 0xffff0000u);
            }
        }
    }
    for (; i < end; ++i) {
        int s = srcs[i];
        if (CPL == 4) {
            uint2 v = *(const uint2*)&U[(size_t)s * D + sub * 4];
            a0 += __uint_as_float(v.x << 16);
            a1 += __uint_as_float(v.x & 0xffff0000u);
            a2 += __uint_as_float(v.y << 16);
            a3 += __uint_as_float(v.y & 0xffff0000u);
        } else {
            uint_t v = *(const uint_t*)&U[(size_t)s * D + sub * 2];
            a0 += __uint_as_float(v << 16);
            a1 += __uint_as_float(v & 0xffff0000u);
        }
    }
    int d = end - beg;
    float inv = 1.f / (float)(d > 1 ? d : 1);
    if (CPL == 4) {
        uint2 p;
        p.x = (uint_t)f2bf(a0 * inv) | ((uint_t)f2bf(a1 * inv) << 16);
        p.y = (uint_t)f2bf(a2 * inv) | ((uint_t)f2bf(a3 * inv) << 16);
        *(uint2*)&out[(size_t)node * D + sub * 4] = p;
    } else {
        uint_t p = (uint_t)f2bf(a0 * inv) | ((uint_t)f2bf(a1 * inv) << 16);
        *(uint_t*)&out[(size_t)node * D + sub * 2] = p;
    }
}

// ---- BN apply + relu + residual(x f32), write bf16 H -----------------------
__global__ __launch_bounds__(256) void k_bnapply(const float* __restrict__ P,
                                                 const float* __restrict__ X,
                                                 const float* __restrict__ stats,
                                                 const float* __restrict__ gamma,
                                                 const float* __restrict__ beta,
                                                 ushort_t* __restrict__ H, int n) {
    int i = blockIdx.x * 256 + threadIdx.x;
    if (i >= n * 64) return;
    int nd = i >> 6;
    int c = (i & 63) << 1;
    float inv_n = 1.f / (float)n;
    float mu0 = stats[c] * inv_n, mu1 = stats[c + 1] * inv_n;
    float v0 = stats[128 + c] * inv_n - mu0 * mu0;
    float v1 = stats[128 + c + 1] * inv_n - mu1 * mu1;
    float s0 = rsqrtf(v0 + WS_EPS) * gamma[c];
    float s1 = rsqrtf(v1 + WS_EPS) * gamma[c + 1];
    float2 p = *(const float2*)&P[(size_t)nd * 128 + c];
    float2 xr = *(const float2*)&X[(size_t)nd * 128 + c];
    float h0 = fmaxf((p.x - mu0) * s0 + beta[c], 0.f) + xr.x;
    float h1 = fmaxf((p.y - mu1) * s1 + beta[c + 1], 0.f) + xr.y;
    uint_t pk = (uint_t)f2bf(h0) | ((uint_t)f2bf(h1) << 16);
    *(uint_t*)&H[(size_t)nd * 128 + c] = pk;
}

// ---------------------------------------------------------------------------
extern "C" void kernel_launch(void* const* d_in, const int* in_sizes, int n_in,
                              void* d_out, int out_size, void* d_ws, size_t ws_size,
                              hipStream_t stream) {
    const float* x     = (const float*)d_in[0];
    const int*   ei    = (const int*)d_in[1];
    const float* Wl0   = (const float*)d_in[2];
    const float* Wr0   = (const float*)d_in[3];
    const float* b0    = (const float*)d_in[4];
    const float* Wl1   = (const float*)d_in[5];
    const float* Wr1   = (const float*)d_in[6];
    const float* b1    = (const float*)d_in[7];
    const float* Wl2   = (const float*)d_in[8];
    const float* Wr2   = (const float*)d_in[9];
    const float* b2    = (const float*)d_in[10];
    const float* gamma = (const float*)d_in[11];
    const float* beta  = (const float*)d_in[12];

    const int n = in_sizes[0] / 128;
    const int E = in_sizes[1] / 2;
    const int nb_scan = (n + SCHUNK - 1) / SCHUNK;

    char* w = (char*)d_ws;
    auto alloc = [&](size_t bytes) -> void* {
        void* p = (void*)w;
        w += (bytes + 255) & ~(size_t)255;
        return p;
    };
    int*      deg   = (int*)alloc((size_t)n * 4);
    int*      cur   = (int*)alloc((size_t)n * 4);
    float*    stats = (float*)alloc(256 * 4);
    size_t    zbytes = (size_t)((char*)w - (char*)deg);
    int*      off   = (int*)alloc(((size_t)n + 1) * 4);
    int*      csr   = (int*)alloc((size_t)E * 4);
    int*      bsum  = (int*)alloc(256 * 4);
    int*      boff  = (int*)alloc(256 * 4);
    ushort_t* wts   = (ushort_t*)alloc((size_t)81920 * 2);
    ushort_t* xb    = (ushort_t*)alloc((size_t)n * 128 * 2);
    ushort_t* H     = (ushort_t*)alloc((size_t)n * 128 * 2);
    float*    P     = (float*)alloc((size_t)n * 128 * 4);
    ushort_t* slabB = (ushort_t*)alloc((size_t)n * 128 * 2);

    ushort_t* WtL0 = wts;
    ushort_t* WtR0 = wts + 16384;
    ushort_t* WtL1 = wts + 32768;
    ushort_t* WtR1 = wts + 49152;
    ushort_t* WtL2 = wts + 65536;
    ushort_t* WtR2 = wts + 73728;

    ushort_t* M   = slabB;
    ushort_t* A64 = slabB;
    ushort_t* B64 = slabB + (size_t)n * 64;

    hipMemsetAsync(deg, 0, zbytes, stream);

    const int eb = (E + 255) / 256;
    k_deg<<<eb, 256, 0, stream>>>(ei, deg, E);
    k_scan_part<<<nb_scan, 256, 0, stream>>>(deg, bsum, n);
    k_scan_bsum<<<1, 64, 0, stream>>>(bsum, boff, off + n, nb_scan);
    k_scan_apply<<<nb_scan, 256, 0, stream>>>(deg, boff, off, n);
    k_scatter<<<eb, 256, 0, stream>>>(ei, off, cur, csr, E);

    const int nb_cvt = (n * 64 + 255) / 256;
    k_prep<<<nb_cvt + 320, 256, 0, stream>>>(x, xb, n * 64, nb_cvt,
                                             Wl0, Wr0, Wl1, Wr1, Wl2, Wr2, wts);

    const int gb = (n + 63) / 64;
    const int smb = (n + 7) / 8;

    // layer 0: M = segmean(xb); H = relu(xb@Wr0 + M@Wl0 + b0)
    k_segmean_bf<128><<<smb, 256, 0, stream>>>(xb, off, csr, M, n);
    k_fgemm<2><<<gb, 256, 0, stream>>>(xb, WtR0, M, WtL0, b0, H, nullptr, n);

    // layer 1: M = segmean(H); P = H@Wr1 + M@Wl1 + b1 (+BN stats);
    //          H = bf16(relu(BN(P)) + x)
    k_segmean_bf<128><<<smb, 256, 0, stream>>>(H, off, csr, M, n);
    k_fgemm<1><<<gb, 256, 0, stream>>>(H, WtR1, M, WtL1, b1, P, stats, n);
    k_bnapply<<<(n * 64 + 255) / 256, 256, 0, stream>>>(P, x, stats, gamma, beta, H, n);

    // layer 2 (commuted; log_softmax fused into final GEMM epilogue)
    k_mgemm64<0><<<gb, 256, 0, stream>>>(H, WtL2, nullptr, nullptr, A64, n);
    k_segmean_bf<64><<<smb, 256, 0, stream>>>(A64, off, csr, B64, n);
    k_mgemm64<3><<<gb, 256, 0, stream>>>(H, WtR2, B64, b2, (float*)d_out, n);
}